// Round 8
// baseline (179.241 us; speedup 1.0000x reference)
//
#include <hip/hip_runtime.h>

#define NPTS 65536
#define MPTS 65536

typedef __attribute__((ext_vector_type(8))) short bf16x8;
typedef __attribute__((ext_vector_type(4))) float f32x4;

__device__ __forceinline__ float bflo(unsigned int u){ union{unsigned int i; float f;} v; v.i = u<<16; return v.f; }
__device__ __forceinline__ float bfhi(unsigned int u){ union{unsigned int i; float f;} v; v.i = u & 0xffff0000u; return v.f; }
__device__ __forceinline__ unsigned short f2bf(float f){
  union{float f; unsigned int i;} v; v.f=f;
  unsigned int r = v.i + 0x7fffu + ((v.i>>16)&1u);  // RNE
  return (unsigned short)(r>>16);
}
__device__ __forceinline__ unsigned int pk2(float a, float b){
  return (unsigned int)f2bf(a) | ((unsigned int)f2bf(b) << 16);
}

#define MFMA32(a,b,c) __builtin_amdgcn_mfma_f32_16x16x32_bf16((a),(b),(c),0,0,0)

// ---- W2 fragment image: 16 frags (kt0..1 x ot0..7), full K=32 ----
__global__ __launch_bounds__(256) void pack_w2(
    const float* __restrict__ W2, unsigned short* __restrict__ W2F) {
  const int gg = blockIdx.x * 256 + threadIdx.x;
  if (gg < 1024) {
    const int g = gg >> 6, lane = gg & 63;
    const int q = (lane & 63) >> 4, lr = lane & 15;
    const int kt = g >> 3, ot = g & 7;
    #pragma unroll
    for (int j = 0; j < 8; ++j)
      W2F[gg*8 + j] = f2bf(W2[(ot*16 + lr)*64 + kt*32 + q*8 + j]);
  }
}

// ---- pack_u: U[n][64] = bf16( W1 . [x_n; pos_n] + b1 ); 16 pts/wave, 1024 blocks ----
__global__ __launch_bounds__(256) void pack_u(
    const float* __restrict__ x,     // [64][N]
    const float* __restrict__ pos,   // [3][N]
    const float* __restrict__ W1,    // [64][67]
    const float* __restrict__ b1,
    unsigned short* __restrict__ U) { // [N][64] bf16
  const int t = threadIdx.x;
  const int lane = t & 63, w = t >> 6, quad = lane >> 4, lr = lane & 15;
  const int nb = blockIdx.x * 64 + w * 16;   // this wave's 16 points
  const int n = nb + lr;

  // A-frags from W1, in-register (L1-hot broadcast loads)
  bf16x8 wa[2][4], wt[4];
  #pragma unroll
  for (int kt = 0; kt < 2; ++kt)
    #pragma unroll
    for (int nt = 0; nt < 4; ++nt) {
      const float* r = W1 + (size_t)(nt*16 + lr)*67 + kt*32 + quad*8;
      const float4 a = *(const float4*)r;
      const float4 b = *(const float4*)(r + 4);
      union { unsigned int d[4]; bf16x8 v; } mk;
      mk.d[0] = pk2(a.x, a.y); mk.d[1] = pk2(a.z, a.w);
      mk.d[2] = pk2(b.x, b.y); mk.d[3] = pk2(b.z, b.w);
      wa[kt][nt] = mk.v;
    }
  #pragma unroll
  for (int nt = 0; nt < 4; ++nt) {           // tail: q=0, j<3 -> c=64..66; else 0
    union { unsigned int d[4]; bf16x8 v; } mk;
    mk.d[0] = 0u; mk.d[1] = 0u; mk.d[2] = 0u; mk.d[3] = 0u;
    if (quad == 0) {
      const float* r = W1 + (size_t)(nt*16 + lr)*67 + 64;
      mk.d[0] = pk2(r[0], r[1]);
      mk.d[1] = (unsigned int)f2bf(r[2]);
    }
    wt[nt] = mk.v;
  }

  const f32x4 fz = {0.f, 0.f, 0.f, 0.f};
  f32x4 acc[4] = {fz, fz, fz, fz};
  #pragma unroll
  for (int kt = 0; kt < 2; ++kt) {
    const float* xc = x + (size_t)(kt*32 + quad*8) * NPTS + n;
    union { unsigned int d[4]; bf16x8 v; } mk;
    #pragma unroll
    for (int i = 0; i < 4; ++i)
      mk.d[i] = pk2(xc[(size_t)(2*i) * NPTS], xc[(size_t)(2*i + 1) * NPTS]);
    #pragma unroll
    for (int nt = 0; nt < 4; ++nt)
      acc[nt] = MFMA32(wa[kt][nt], mk.v, acc[nt]);
  }
  {
    union { unsigned int d[4]; bf16x8 v; } mk;
    mk.d[0] = pk2(pos[n], pos[NPTS + n]);
    mk.d[1] = (unsigned int)f2bf(pos[2*NPTS + n]);
    mk.d[2] = 0u; mk.d[3] = 0u;
    #pragma unroll
    for (int nt = 0; nt < 4; ++nt)
      acc[nt] = MFMA32(wt[nt], mk.v, acc[nt]);
  }
  // store: lane holds h = nt*16+quad*4+r for point col lr
  #pragma unroll
  for (int nt = 0; nt < 4; ++nt) {
    const float4 bb = *(const float4*)(b1 + nt*16 + quad*4);
    uint2 d;
    d.x = pk2(acc[nt][0] + bb.x, acc[nt][1] + bb.y);
    d.y = pk2(acc[nt][2] + bb.z, acc[nt][3] + bb.w);
    *(uint2*)(U + (size_t)n * 64 + nt*16 + quad*4) = d;
  }
}

// ---- main: LDS-free. 16B-granular gather -> relu(u-v) in-register -> MFMA -> max-K ----
__global__ __launch_bounds__(256, 5) void pointnet_reg(
    const unsigned short* __restrict__ U,    // [N][64] bf16
    const float* __restrict__ sup,           // [3][M]
    const float* __restrict__ W1,            // [64][67] (W1p cols 64..66)
    const unsigned short* __restrict__ W2F,
    const float* __restrict__ b2,
    const int* __restrict__ indices,         // [M][16]
    float* __restrict__ out) {               // [128][M]
  const int t = threadIdx.x;
  const int m0 = blockIdx.x * 16;
  const int lane = t & 63, w = t >> 6, quad = lane >> 4, lr = lane & 15;
  const int wbase = m0 + w*4;                // this wave's 4 support points

  // indices: lane lr = neighbor k of m = wbase+pt
  int idx[4];
  #pragma unroll
  for (int pt = 0; pt < 4; ++pt) idx[pt] = indices[(wbase + pt)*16 + lr];

  // issue all 8 gather loads (each 16B = the exact MFMA fragment slice)
  uint4 ur[4][2];
  #pragma unroll
  for (int pt = 0; pt < 4; ++pt)
    #pragma unroll
    for (int kt = 0; kt < 2; ++kt)
      ur[pt][kt] = *(const uint4*)(U + (size_t)idx[pt]*64 + kt*32 + quad*8);

  // sup (wave-uniform per pt)
  float s0[4], s1[4], s2[4];
  #pragma unroll
  for (int pt = 0; pt < 4; ++pt) {
    s0[pt] = sup[wbase + pt];
    s1[pt] = sup[MPTS + wbase + pt];
    s2[pt] = sup[2*MPTS + wbase + pt];
  }

  // h = relu(u - W1p.s) packed into A-frags
  bf16x8 ah[4][2];
  #pragma unroll
  for (int kt = 0; kt < 2; ++kt) {
    float w1p[8][3];                          // rows h = kt*32 + quad*8 + j (L1-hot)
    #pragma unroll
    for (int j = 0; j < 8; ++j) {
      const float* r = W1 + (size_t)(kt*32 + quad*8 + j)*67 + 64;
      w1p[j][0] = r[0]; w1p[j][1] = r[1]; w1p[j][2] = r[2];
    }
    #pragma unroll
    for (int pt = 0; pt < 4; ++pt) {
      const unsigned int uu[4] = {ur[pt][kt].x, ur[pt][kt].y, ur[pt][kt].z, ur[pt][kt].w};
      union { unsigned int d[4]; bf16x8 v; } mk;
      #pragma unroll
      for (int i = 0; i < 4; ++i) {
        const float vl = w1p[2*i][0]*s0[pt] + w1p[2*i][1]*s1[pt] + w1p[2*i][2]*s2[pt];
        const float vh = w1p[2*i+1][0]*s0[pt] + w1p[2*i+1][1]*s1[pt] + w1p[2*i+1][2]*s2[pt];
        const float hl = fmaxf(bflo(uu[i]) - vl, 0.f);
        const float hh = fmaxf(bfhi(uu[i]) - vh, 0.f);
        mk.d[i] = pk2(hl, hh);
      }
      ah[pt][kt] = mk.v;
    }
  }

  // stage 2: D2[point][o], full-K; k-max across rows; direct store
  const f32x4 fz = {0.f, 0.f, 0.f, 0.f};
  #pragma unroll
  for (int ot = 0; ot < 8; ++ot) {
    const bf16x8 wb0 = ((const bf16x8*)W2F)[(0*8 + ot)*64 + lane];
    const bf16x8 wb1 = ((const bf16x8*)W2F)[(1*8 + ot)*64 + lane];
    f32x4 a2[4];
    #pragma unroll
    for (int pt = 0; pt < 4; ++pt) {
      a2[pt] = MFMA32(ah[pt][0], wb0, fz);
      a2[pt] = MFMA32(ah[pt][1], wb1, a2[pt]);
    }
    float vm[4];
    #pragma unroll
    for (int pt = 0; pt < 4; ++pt) {
      float v = fmaxf(fmaxf(a2[pt][0], a2[pt][1]), fmaxf(a2[pt][2], a2[pt][3]));
      v = fmaxf(v, __shfl_xor(v, 16));
      v = fmaxf(v, __shfl_xor(v, 32));
      vm[pt] = v;
    }
    const float vq = (quad & 1) ? ((quad & 2) ? vm[3] : vm[1])
                                : ((quad & 2) ? vm[2] : vm[0]);
    const int o = ot*16 + lr;
    out[(size_t)o * MPTS + wbase + quad] = vq + b2[o];
  }
}

// ---- fallback (ws too small): direct fp32 kernel, known-correct ----
__global__ __launch_bounds__(256) void pointnet_fallback(
    const float* __restrict__ x, const float* __restrict__ pos,
    const float* __restrict__ sup,
    const float* __restrict__ W1, const float* __restrict__ b1,
    const float* __restrict__ W2, const float* __restrict__ b2,
    const int* __restrict__ indices, float* __restrict__ out) {
  __shared__ float sfeat[16][68];
  __shared__ float shid[16][64];
  __shared__ float smax[4][128];
  __shared__ int sidx[16];
  const int t = threadIdx.x;
  const int m = blockIdx.x;
  if (t < 16) sidx[t] = indices[m*16 + t];
  const float sup0 = sup[m], sup1 = sup[MPTS + m], sup2 = sup[2*MPTS + m];
  __syncthreads();
  for (int u = t; u < 16*17; u += 256) {
    const int k = u / 17, c4 = (u - k*17) * 4;
    const int idx = sidx[k];
    float4 wv;
    if (c4 < 64) {
      wv.x = x[(size_t)(c4+0)*NPTS + idx]; wv.y = x[(size_t)(c4+1)*NPTS + idx];
      wv.z = x[(size_t)(c4+2)*NPTS + idx]; wv.w = x[(size_t)(c4+3)*NPTS + idx];
    } else {
      wv.x = pos[idx] - sup0; wv.y = pos[NPTS + idx] - sup1;
      wv.z = pos[2*NPTS + idx] - sup2; wv.w = 0.f;
    }
    *(float4*)&sfeat[k][c4] = wv;
  }
  const int h = t & 63, kg = t >> 6;
  float w1r[68];
  #pragma unroll
  for (int c = 0; c < 67; ++c) w1r[c] = W1[h*67 + c];
  w1r[67] = 0.f;
  const float bias1 = b1[h];
  __syncthreads();
  #pragma unroll
  for (int j = 0; j < 4; ++j) {
    const int k = kg*4 + j;
    float a = bias1;
    const float4* rr = (const float4*)sfeat[k];
    #pragma unroll
    for (int qq = 0; qq < 17; ++qq) {
      const float4 v = rr[qq];
      a += w1r[qq*4+0]*v.x + w1r[qq*4+1]*v.y + w1r[qq*4+2]*v.z + w1r[qq*4+3]*v.w;
    }
    shid[k][h] = fmaxf(a, 0.f);
  }
  const int ow = t & 63;
  float w2a[64], w2b[64];
  #pragma unroll
  for (int hh = 0; hh < 64; ++hh) { w2a[hh] = W2[ow*64 + hh]; w2b[hh] = W2[(ow+64)*64 + hh]; }
  __syncthreads();
  float mxa = -3.0e38f, mxb = -3.0e38f;
  #pragma unroll
  for (int j = 0; j < 4; ++j) {
    const int k = kg*4 + j;
    const float4* hr = (const float4*)shid[k];
    float pa = 0.f, pb = 0.f;
    #pragma unroll
    for (int qq = 0; qq < 16; ++qq) {
      const float4 v = hr[qq];
      pa += w2a[qq*4+0]*v.x + w2a[qq*4+1]*v.y + w2a[qq*4+2]*v.z + w2a[qq*4+3]*v.w;
      pb += w2b[qq*4+0]*v.x + w2b[qq*4+1]*v.y + w2b[qq*4+2]*v.z + w2b[qq*4+3]*v.w;
    }
    mxa = fmaxf(mxa, pa); mxb = fmaxf(mxb, pb);
  }
  smax[kg][ow] = mxa; smax[kg][64 + ow] = mxb;
  __syncthreads();
  if (t < 128) {
    out[(size_t)t * MPTS + m] =
        fmaxf(fmaxf(smax[0][t], smax[1][t]), fmaxf(smax[2][t], smax[3][t])) + b2[t];
  }
}

extern "C" void kernel_launch(void* const* d_in, const int* in_sizes, int n_in,
                              void* d_out, int out_size, void* d_ws, size_t ws_size,
                              hipStream_t stream) {
  const float* x   = (const float*)d_in[0];
  const float* pos = (const float*)d_in[1];
  const float* sup = (const float*)d_in[2];
  const float* W1  = (const float*)d_in[3];
  const float* b1  = (const float*)d_in[4];
  const float* W2  = (const float*)d_in[5];
  const float* b2  = (const float*)d_in[6];
  const int* indices = (const int*)d_in[7];
  float* out = (float*)d_out;

  const size_t U_BYTES   = (size_t)NPTS * 64 * 2;     // 8,388,608
  const size_t W2F_BYTES = 16 * 64 * 8 * 2;           // 16,384
  if (ws_size >= U_BYTES + W2F_BYTES) {
    unsigned short* U   = (unsigned short*)d_ws;
    unsigned short* W2F = (unsigned short*)((char*)d_ws + U_BYTES);
    pack_w2<<<4, 256, 0, stream>>>(W2, W2F);
    pack_u<<<NPTS/64, 256, 0, stream>>>(x, pos, W1, b1, U);
    pointnet_reg<<<MPTS/16, 256, 0, stream>>>(U, sup, W1, W2F, b2, indices, out);
  } else {
    pointnet_fallback<<<MPTS, 256, 0, stream>>>(x, pos, sup, W1, b1, W2, b2, indices, out);
  }
}

// Round 9
// 144.318 us; speedup vs baseline: 1.2420x; 1.2420x over previous
//
#include <hip/hip_runtime.h>

#define NPTS 65536
#define MPTS 65536

typedef __attribute__((ext_vector_type(8))) short bf16x8;
typedef __attribute__((ext_vector_type(4))) float f32x4;

__device__ __forceinline__ float bflo(unsigned int u){ union{unsigned int i; float f;} v; v.i = u<<16; return v.f; }
__device__ __forceinline__ float bfhi(unsigned int u){ union{unsigned int i; float f;} v; v.i = u & 0xffff0000u; return v.f; }
__device__ __forceinline__ unsigned short f2bf(float f){
  union{float f; unsigned int i;} v; v.f=f;
  unsigned int r = v.i + 0x7fffu + ((v.i>>16)&1u);  // RNE
  return (unsigned short)(r>>16);
}
__device__ __forceinline__ unsigned int pk2(float a, float b){
  return (unsigned int)f2bf(a) | ((unsigned int)f2bf(b) << 16);
}

#define MFMA32(a,b,c) __builtin_amdgcn_mfma_f32_16x16x32_bf16((a),(b),(c),0,0,0)

// ---- pack_u: U[n][64] = bf16( W1 . [x_n; pos_n] + b1 ); blocks >=1024 pack W2F ----
__global__ __launch_bounds__(256) void pack_u(
    const float* __restrict__ x,     // [64][N]
    const float* __restrict__ pos,   // [3][N]
    const float* __restrict__ W1,    // [64][67]
    const float* __restrict__ b1,
    const float* __restrict__ W2,    // [128][64]
    unsigned short* __restrict__ U,  // [N][64] bf16
    unsigned short* __restrict__ W2F) {
  const int t = threadIdx.x;
  if (blockIdx.x >= 1024) {          // W2 fragment image: 16 frags (kt x ot), full K=32
    const int gg = (blockIdx.x - 1024) * 256 + t;
    if (gg < 1024) {
      const int g = gg >> 6, lane = gg & 63;
      const int q = lane >> 4, lr = lane & 15;
      const int kt = g >> 3, ot = g & 7;
      #pragma unroll
      for (int j = 0; j < 8; ++j)
        W2F[gg*8 + j] = f2bf(W2[(ot*16 + lr)*64 + kt*32 + q*8 + j]);
    }
    return;
  }
  const int lane = t & 63, w = t >> 6, quad = lane >> 4, lr = lane & 15;
  const int n = blockIdx.x * 64 + w * 16 + lr;

  // A-frags from W1, in-register (L1-hot broadcast loads)
  bf16x8 wa[2][4], wt[4];
  #pragma unroll
  for (int kt = 0; kt < 2; ++kt)
    #pragma unroll
    for (int nt = 0; nt < 4; ++nt) {
      const float* r = W1 + (size_t)(nt*16 + lr)*67 + kt*32 + quad*8;
      const float4 a = *(const float4*)r;
      const float4 b = *(const float4*)(r + 4);
      union { unsigned int d[4]; bf16x8 v; } mk;
      mk.d[0] = pk2(a.x, a.y); mk.d[1] = pk2(a.z, a.w);
      mk.d[2] = pk2(b.x, b.y); mk.d[3] = pk2(b.z, b.w);
      wa[kt][nt] = mk.v;
    }
  #pragma unroll
  for (int nt = 0; nt < 4; ++nt) {   // tail: quad0, j<3 -> c=64..66; else 0
    union { unsigned int d[4]; bf16x8 v; } mk;
    mk.d[0] = 0u; mk.d[1] = 0u; mk.d[2] = 0u; mk.d[3] = 0u;
    if (quad == 0) {
      const float* r = W1 + (size_t)(nt*16 + lr)*67 + 64;
      mk.d[0] = pk2(r[0], r[1]);
      mk.d[1] = (unsigned int)f2bf(r[2]);
    }
    wt[nt] = mk.v;
  }

  const f32x4 fz = {0.f, 0.f, 0.f, 0.f};
  f32x4 acc[4] = {fz, fz, fz, fz};
  #pragma unroll
  for (int kt = 0; kt < 2; ++kt) {
    const float* xc = x + (size_t)(kt*32 + quad*8) * NPTS + n;
    union { unsigned int d[4]; bf16x8 v; } mk;
    #pragma unroll
    for (int i = 0; i < 4; ++i)
      mk.d[i] = pk2(xc[(size_t)(2*i) * NPTS], xc[(size_t)(2*i + 1) * NPTS]);
    #pragma unroll
    for (int nt = 0; nt < 4; ++nt)
      acc[nt] = MFMA32(wa[kt][nt], mk.v, acc[nt]);
  }
  {
    union { unsigned int d[4]; bf16x8 v; } mk;
    mk.d[0] = pk2(pos[n], pos[NPTS + n]);
    mk.d[1] = (unsigned int)f2bf(pos[2*NPTS + n]);
    mk.d[2] = 0u; mk.d[3] = 0u;
    #pragma unroll
    for (int nt = 0; nt < 4; ++nt)
      acc[nt] = MFMA32(wt[nt], mk.v, acc[nt]);
  }
  // store: lane holds h = nt*16+quad*4+r for point col lr
  #pragma unroll
  for (int nt = 0; nt < 4; ++nt) {
    const float4 bb = *(const float4*)(b1 + nt*16 + quad*4);
    uint2 d;
    d.x = pk2(acc[nt][0] + bb.x, acc[nt][1] + bb.y);
    d.y = pk2(acc[nt][2] + bb.z, acc[nt][3] + bb.w);
    *(uint2*)(U + (size_t)n * 64 + nt*16 + quad*4) = d;
  }
}

// ---- main: LDS-free. 16B-granular gather -> relu(u-v) in-register -> MFMA -> max-K ----
__global__ __launch_bounds__(256, 4) void pointnet_reg(
    const unsigned short* __restrict__ U,    // [N][64] bf16
    const float* __restrict__ sup,           // [3][M]
    const float* __restrict__ W1,            // [64][67] (W1p cols 64..66)
    const unsigned short* __restrict__ W2F,
    const float* __restrict__ b2,
    const int* __restrict__ indices,         // [M][16]
    float* __restrict__ out) {               // [128][M]
  const int t = threadIdx.x;
  const int m0 = blockIdx.x * 16;
  const int lane = t & 63, w = t >> 6, quad = lane >> 4, lr = lane & 15;
  const int wbase = m0 + w*4;                // this wave's 4 support points

  // indices: lane lr = neighbor k of m = wbase+pt
  int idx[4];
  #pragma unroll
  for (int pt = 0; pt < 4; ++pt) idx[pt] = indices[(wbase + pt)*16 + lr];

  // issue all 8 gather loads (each 16B = the exact MFMA fragment slice)
  uint4 ur[4][2];
  #pragma unroll
  for (int pt = 0; pt < 4; ++pt)
    #pragma unroll
    for (int kt = 0; kt < 2; ++kt)
      ur[pt][kt] = *(const uint4*)(U + (size_t)idx[pt]*64 + kt*32 + quad*8);

  // sup (wave-uniform per pt)
  float s0[4], s1[4], s2[4];
  #pragma unroll
  for (int pt = 0; pt < 4; ++pt) {
    s0[pt] = sup[wbase + pt];
    s1[pt] = sup[MPTS + wbase + pt];
    s2[pt] = sup[2*MPTS + wbase + pt];
  }

  // h = relu(u - W1p.s) packed into A-frags
  bf16x8 ah[4][2];
  #pragma unroll
  for (int kt = 0; kt < 2; ++kt) {
    float w1p[8][3];                          // rows h = kt*32 + quad*8 + j (L1-hot)
    #pragma unroll
    for (int j = 0; j < 8; ++j) {
      const float* r = W1 + (size_t)(kt*32 + quad*8 + j)*67 + 64;
      w1p[j][0] = r[0]; w1p[j][1] = r[1]; w1p[j][2] = r[2];
    }
    #pragma unroll
    for (int pt = 0; pt < 4; ++pt) {
      const unsigned int uu[4] = {ur[pt][kt].x, ur[pt][kt].y, ur[pt][kt].z, ur[pt][kt].w};
      union { unsigned int d[4]; bf16x8 v; } mk;
      #pragma unroll
      for (int i = 0; i < 4; ++i) {
        const float vl = w1p[2*i][0]*s0[pt] + w1p[2*i][1]*s1[pt] + w1p[2*i][2]*s2[pt];
        const float vh = w1p[2*i+1][0]*s0[pt] + w1p[2*i+1][1]*s1[pt] + w1p[2*i+1][2]*s2[pt];
        const float hl = fmaxf(bflo(uu[i]) - vl, 0.f);
        const float hh = fmaxf(bfhi(uu[i]) - vh, 0.f);
        mk.d[i] = pk2(hl, hh);
      }
      ah[pt][kt] = mk.v;
    }
  }

  // stage 2: D2[point][o], full-K; k-max across rows; direct store
  const f32x4 fz = {0.f, 0.f, 0.f, 0.f};
  #pragma unroll
  for (int ot = 0; ot < 8; ++ot) {
    const bf16x8 wb0 = ((const bf16x8*)W2F)[(0*8 + ot)*64 + lane];
    const bf16x8 wb1 = ((const bf16x8*)W2F)[(1*8 + ot)*64 + lane];
    f32x4 a2[4];
    #pragma unroll
    for (int pt = 0; pt < 4; ++pt) {
      a2[pt] = MFMA32(ah[pt][0], wb0, fz);
      a2[pt] = MFMA32(ah[pt][1], wb1, a2[pt]);
    }
    float vm[4];
    #pragma unroll
    for (int pt = 0; pt < 4; ++pt) {
      float v = fmaxf(fmaxf(a2[pt][0], a2[pt][1]), fmaxf(a2[pt][2], a2[pt][3]));
      v = fmaxf(v, __shfl_xor(v, 16));
      v = fmaxf(v, __shfl_xor(v, 32));
      vm[pt] = v;
    }
    const float vq = (quad & 1) ? ((quad & 2) ? vm[3] : vm[1])
                                : ((quad & 2) ? vm[2] : vm[0]);
    const int o = ot*16 + lr;
    out[(size_t)o * MPTS + wbase + quad] = vq + b2[o];
  }
}

// ---- fallback (ws too small): direct fp32 kernel, known-correct ----
__global__ __launch_bounds__(256) void pointnet_fallback(
    const float* __restrict__ x, const float* __restrict__ pos,
    const float* __restrict__ sup,
    const float* __restrict__ W1, const float* __restrict__ b1,
    const float* __restrict__ W2, const float* __restrict__ b2,
    const int* __restrict__ indices, float* __restrict__ out) {
  __shared__ float sfeat[16][68];
  __shared__ float shid[16][64];
  __shared__ float smax[4][128];
  __shared__ int sidx[16];
  const int t = threadIdx.x;
  const int m = blockIdx.x;
  if (t < 16) sidx[t] = indices[m*16 + t];
  const float sup0 = sup[m], sup1 = sup[MPTS + m], sup2 = sup[2*MPTS + m];
  __syncthreads();
  for (int u = t; u < 16*17; u += 256) {
    const int k = u / 17, c4 = (u - k*17) * 4;
    const int idx = sidx[k];
    float4 wv;
    if (c4 < 64) {
      wv.x = x[(size_t)(c4+0)*NPTS + idx]; wv.y = x[(size_t)(c4+1)*NPTS + idx];
      wv.z = x[(size_t)(c4+2)*NPTS + idx]; wv.w = x[(size_t)(c4+3)*NPTS + idx];
    } else {
      wv.x = pos[idx] - sup0; wv.y = pos[NPTS + idx] - sup1;
      wv.z = pos[2*NPTS + idx] - sup2; wv.w = 0.f;
    }
    *(float4*)&sfeat[k][c4] = wv;
  }
  const int h = t & 63, kg = t >> 6;
  float w1r[68];
  #pragma unroll
  for (int c = 0; c < 67; ++c) w1r[c] = W1[h*67 + c];
  w1r[67] = 0.f;
  const float bias1 = b1[h];
  __syncthreads();
  #pragma unroll
  for (int j = 0; j < 4; ++j) {
    const int k = kg*4 + j;
    float a = bias1;
    const float4* rr = (const float4*)sfeat[k];
    #pragma unroll
    for (int qq = 0; qq < 17; ++qq) {
      const float4 v = rr[qq];
      a += w1r[qq*4+0]*v.x + w1r[qq*4+1]*v.y + w1r[qq*4+2]*v.z + w1r[qq*4+3]*v.w;
    }
    shid[k][h] = fmaxf(a, 0.f);
  }
  const int ow = t & 63;
  float w2a[64], w2b[64];
  #pragma unroll
  for (int hh = 0; hh < 64; ++hh) { w2a[hh] = W2[ow*64 + hh]; w2b[hh] = W2[(ow+64)*64 + hh]; }
  __syncthreads();
  float mxa = -3.0e38f, mxb = -3.0e38f;
  #pragma unroll
  for (int j = 0; j < 4; ++j) {
    const int k = kg*4 + j;
    const float4* hr = (const float4*)shid[k];
    float pa = 0.f, pb = 0.f;
    #pragma unroll
    for (int qq = 0; qq < 16; ++qq) {
      const float4 v = hr[qq];
      pa += w2a[qq*4+0]*v.x + w2a[qq*4+1]*v.y + w2a[qq*4+2]*v.z + w2a[qq*4+3]*v.w;
      pb += w2b[qq*4+0]*v.x + w2b[qq*4+1]*v.y + w2b[qq*4+2]*v.z + w2b[qq*4+3]*v.w;
    }
    mxa = fmaxf(mxa, pa); mxb = fmaxf(mxb, pb);
  }
  smax[kg][ow] = mxa; smax[kg][64 + ow] = mxb;
  __syncthreads();
  if (t < 128) {
    out[(size_t)t * MPTS + m] =
        fmaxf(fmaxf(smax[0][t], smax[1][t]), fmaxf(smax[2][t], smax[3][t])) + b2[t];
  }
}

extern "C" void kernel_launch(void* const* d_in, const int* in_sizes, int n_in,
                              void* d_out, int out_size, void* d_ws, size_t ws_size,
                              hipStream_t stream) {
  const float* x   = (const float*)d_in[0];
  const float* pos = (const float*)d_in[1];
  const float* sup = (const float*)d_in[2];
  const float* W1  = (const float*)d_in[3];
  const float* b1  = (const float*)d_in[4];
  const float* W2  = (const float*)d_in[5];
  const float* b2  = (const float*)d_in[6];
  const int* indices = (const int*)d_in[7];
  float* out = (float*)d_out;

  const size_t U_BYTES   = (size_t)NPTS * 64 * 2;     // 8,388,608
  const size_t W2F_BYTES = 16 * 64 * 8 * 2;           // 16,384
  if (ws_size >= U_BYTES + W2F_BYTES) {
    unsigned short* U   = (unsigned short*)d_ws;
    unsigned short* W2F = (unsigned short*)((char*)d_ws + U_BYTES);
    pack_u<<<NPTS/64 + 4, 256, 0, stream>>>(x, pos, W1, b1, W2, U, W2F);
    pointnet_reg<<<MPTS/16, 256, 0, stream>>>(U, sup, W1, W2F, b2, indices, out);
  } else {
    pointnet_fallback<<<MPTS, 256, 0, stream>>>(x, pos, sup, W1, b1, W2, b2, indices, out);
  }
}

// Round 10
// 136.021 us; speedup vs baseline: 1.3178x; 1.0610x over previous
//
#include <hip/hip_runtime.h>
#include <hip/hip_bf16.h>

#define NPTS 65536
#define MPTS 65536

typedef __attribute__((ext_vector_type(8))) short bf16x8;
typedef __attribute__((ext_vector_type(4))) float f32x4;

__device__ __forceinline__ float bflo(unsigned int u){ union{unsigned int i; float f;} v; v.i = u<<16; return v.f; }
__device__ __forceinline__ float bfhi(unsigned int u){ union{unsigned int i; float f;} v; v.i = u & 0xffff0000u; return v.f; }
__device__ __forceinline__ unsigned short f2bf(float f){
  union{float f; unsigned int i;} v; v.f=f;
  unsigned int r = v.i + 0x7fffu + ((v.i>>16)&1u);  // RNE
  return (unsigned short)(r>>16);
}
// packed RNE convert: 2 fp32 -> 1 dword of 2 bf16 (v_cvt_pk_bf16_f32 on gfx950)
__device__ __forceinline__ unsigned int pk2f(float a, float b){
  float2 tf; tf.x = a; tf.y = b;
  union { __hip_bfloat162 h; unsigned int u; } c;
  c.h = __float22bfloat162_rn(tf);
  return c.u;
}

#define MFMA32(a,b,c) __builtin_amdgcn_mfma_f32_16x16x32_bf16((a),(b),(c),0,0,0)

// ---- pack_u: U[n][64] = bf16( W1 . [x_n; pos_n] + b1 ); blocks >=1024 pack W2F ----
__global__ __launch_bounds__(256) void pack_u(
    const float* __restrict__ x,     // [64][N]
    const float* __restrict__ pos,   // [3][N]
    const float* __restrict__ W1,    // [64][67]
    const float* __restrict__ b1,
    const float* __restrict__ W2,    // [128][64]
    unsigned short* __restrict__ U,  // [N][64] bf16
    unsigned short* __restrict__ W2F) {
  const int t = threadIdx.x;
  if (blockIdx.x >= 1024) {          // W2 fragment image: 16 frags (kt x ot), full K=32
    const int gg = (blockIdx.x - 1024) * 256 + t;
    if (gg < 1024) {
      const int g = gg >> 6, lane = gg & 63;
      const int q = lane >> 4, lr = lane & 15;
      const int kt = g >> 3, ot = g & 7;
      #pragma unroll
      for (int j = 0; j < 4; ++j)
        *(unsigned int*)&W2F[gg*8 + 2*j] =
            pk2f(W2[(ot*16 + lr)*64 + kt*32 + q*8 + 2*j],
                 W2[(ot*16 + lr)*64 + kt*32 + q*8 + 2*j + 1]);
    }
    return;
  }
  const int lane = t & 63, w = t >> 6, quad = lane >> 4, lr = lane & 15;
  const int n = blockIdx.x * 64 + w * 16 + lr;

  // A-frags from W1, in-register (L1-hot broadcast loads)
  bf16x8 wa[2][4], wt[4];
  #pragma unroll
  for (int kt = 0; kt < 2; ++kt)
    #pragma unroll
    for (int nt = 0; nt < 4; ++nt) {
      const float* r = W1 + (size_t)(nt*16 + lr)*67 + kt*32 + quad*8;
      const float4 a = *(const float4*)r;
      const float4 b = *(const float4*)(r + 4);
      union { unsigned int d[4]; bf16x8 v; } mk;
      mk.d[0] = pk2f(a.x, a.y); mk.d[1] = pk2f(a.z, a.w);
      mk.d[2] = pk2f(b.x, b.y); mk.d[3] = pk2f(b.z, b.w);
      wa[kt][nt] = mk.v;
    }
  #pragma unroll
  for (int nt = 0; nt < 4; ++nt) {   // tail: quad0, j<3 -> c=64..66; else 0
    union { unsigned int d[4]; bf16x8 v; } mk;
    mk.d[0] = 0u; mk.d[1] = 0u; mk.d[2] = 0u; mk.d[3] = 0u;
    if (quad == 0) {
      const float* r = W1 + (size_t)(nt*16 + lr)*67 + 64;
      mk.d[0] = pk2f(r[0], r[1]);
      mk.d[1] = (unsigned int)f2bf(r[2]);
    }
    wt[nt] = mk.v;
  }

  const f32x4 fz = {0.f, 0.f, 0.f, 0.f};
  f32x4 acc[4] = {fz, fz, fz, fz};
  #pragma unroll
  for (int kt = 0; kt < 2; ++kt) {
    const float* xc = x + (size_t)(kt*32 + quad*8) * NPTS + n;
    union { unsigned int d[4]; bf16x8 v; } mk;
    #pragma unroll
    for (int i = 0; i < 4; ++i)
      mk.d[i] = pk2f(xc[(size_t)(2*i) * NPTS], xc[(size_t)(2*i + 1) * NPTS]);
    #pragma unroll
    for (int nt = 0; nt < 4; ++nt)
      acc[nt] = MFMA32(wa[kt][nt], mk.v, acc[nt]);
  }
  {
    union { unsigned int d[4]; bf16x8 v; } mk;
    mk.d[0] = pk2f(pos[n], pos[NPTS + n]);
    mk.d[1] = (unsigned int)f2bf(pos[2*NPTS + n]);
    mk.d[2] = 0u; mk.d[3] = 0u;
    #pragma unroll
    for (int nt = 0; nt < 4; ++nt)
      acc[nt] = MFMA32(wt[nt], mk.v, acc[nt]);
  }
  // store: lane holds h = nt*16+quad*4+r for point col lr
  #pragma unroll
  for (int nt = 0; nt < 4; ++nt) {
    const float4 bb = *(const float4*)(b1 + nt*16 + quad*4);
    uint2 d;
    d.x = pk2f(acc[nt][0] + bb.x, acc[nt][1] + bb.y);
    d.y = pk2f(acc[nt][2] + bb.z, acc[nt][3] + bb.w);
    *(uint2*)(U + (size_t)n * 64 + nt*16 + quad*4) = d;
  }
}

// ---- main: LDS-free, 8 support points per wave, 16 gathers in flight ----
__global__ __launch_bounds__(256, 3) void pointnet_reg(
    const unsigned short* __restrict__ U,    // [N][64] bf16
    const float* __restrict__ sup,           // [3][M]
    const float* __restrict__ W1,            // [64][67] (W1p cols 64..66)
    const unsigned short* __restrict__ W2F,
    const float* __restrict__ b2,
    const int* __restrict__ indices,         // [M][16]
    float* __restrict__ out) {               // [128][M]
  const int t = threadIdx.x;
  const int lane = t & 63, w = t >> 6, quad = lane >> 4, lr = lane & 15;
  const int wbase = blockIdx.x * 32 + w * 8; // this wave's 8 support points

  // indices: lane lr = neighbor k of m = wbase+pt
  int idx[8];
  #pragma unroll
  for (int pt = 0; pt < 8; ++pt) idx[pt] = indices[(wbase + pt)*16 + lr];

  // issue all 16 gather loads (each 16B = the exact MFMA fragment slice)
  uint4 ur[8][2];
  #pragma unroll
  for (int pt = 0; pt < 8; ++pt)
    #pragma unroll
    for (int kt = 0; kt < 2; ++kt)
      ur[pt][kt] = *(const uint4*)(U + (size_t)idx[pt]*64 + kt*32 + quad*8);

  // h = relu(u - W1p.s) packed into A-frags; kt outer keeps w1p small
  bf16x8 ah[8][2];
  #pragma unroll
  for (int kt = 0; kt < 2; ++kt) {
    float w1p[8][3];                         // rows h = kt*32 + quad*8 + j (L1-hot)
    #pragma unroll
    for (int j = 0; j < 8; ++j) {
      const float* r = W1 + (size_t)(kt*32 + quad*8 + j)*67 + 64;
      w1p[j][0] = r[0]; w1p[j][1] = r[1]; w1p[j][2] = r[2];
    }
    #pragma unroll
    for (int pt = 0; pt < 8; ++pt) {
      const float s0 = sup[wbase + pt];
      const float s1 = sup[MPTS + wbase + pt];
      const float s2 = sup[2*MPTS + wbase + pt];
      const unsigned int uu[4] = {ur[pt][kt].x, ur[pt][kt].y, ur[pt][kt].z, ur[pt][kt].w};
      union { unsigned int d[4]; bf16x8 v; } mk;
      #pragma unroll
      for (int i = 0; i < 4; ++i) {
        const float vl = w1p[2*i][0]*s0 + w1p[2*i][1]*s1 + w1p[2*i][2]*s2;
        const float vh = w1p[2*i+1][0]*s0 + w1p[2*i+1][1]*s1 + w1p[2*i+1][2]*s2;
        const float hl = fmaxf(bflo(uu[i]) - vl, 0.f);
        const float hh = fmaxf(bfhi(uu[i]) - vh, 0.f);
        mk.d[i] = pk2f(hl, hh);
      }
      ah[pt][kt] = mk.v;
    }
  }

  // stage 2: per ot, 16 MFMAs (8 independent 2-chains); k-max; 2 stores/lane
  const f32x4 fz = {0.f, 0.f, 0.f, 0.f};
  #pragma unroll
  for (int ot = 0; ot < 8; ++ot) {
    const bf16x8 wb0 = ((const bf16x8*)W2F)[(0*8 + ot)*64 + lane];
    const bf16x8 wb1 = ((const bf16x8*)W2F)[(1*8 + ot)*64 + lane];
    float vm[8];
    #pragma unroll
    for (int pt = 0; pt < 8; ++pt) {
      f32x4 a2 = MFMA32(ah[pt][0], wb0, fz);
      a2 = MFMA32(ah[pt][1], wb1, a2);
      float v = fmaxf(fmaxf(a2[0], a2[1]), fmaxf(a2[2], a2[3]));
      v = fmaxf(v, __shfl_xor(v, 16));
      v = fmaxf(v, __shfl_xor(v, 32));
      vm[pt] = v;
    }
    const int o = ot*16 + lr;
    const float bb = b2[o];
    const float va = (quad & 1) ? ((quad & 2) ? vm[3] : vm[1])
                                : ((quad & 2) ? vm[2] : vm[0]);
    const float vb = (quad & 1) ? ((quad & 2) ? vm[7] : vm[5])
                                : ((quad & 2) ? vm[6] : vm[4]);
    out[(size_t)o * MPTS + wbase + quad] = va + bb;
    out[(size_t)o * MPTS + wbase + 4 + quad] = vb + bb;
  }
}

// ---- fallback (ws too small): direct fp32 kernel, known-correct ----
__global__ __launch_bounds__(256) void pointnet_fallback(
    const float* __restrict__ x, const float* __restrict__ pos,
    const float* __restrict__ sup,
    const float* __restrict__ W1, const float* __restrict__ b1,
    const float* __restrict__ W2, const float* __restrict__ b2,
    const int* __restrict__ indices, float* __restrict__ out) {
  __shared__ float sfeat[16][68];
  __shared__ float shid[16][64];
  __shared__ float smax[4][128];
  __shared__ int sidx[16];
  const int t = threadIdx.x;
  const int m = blockIdx.x;
  if (t < 16) sidx[t] = indices[m*16 + t];
  const float sup0 = sup[m], sup1 = sup[MPTS + m], sup2 = sup[2*MPTS + m];
  __syncthreads();
  for (int u = t; u < 16*17; u += 256) {
    const int k = u / 17, c4 = (u - k*17) * 4;
    const int idx = sidx[k];
    float4 wv;
    if (c4 < 64) {
      wv.x = x[(size_t)(c4+0)*NPTS + idx]; wv.y = x[(size_t)(c4+1)*NPTS + idx];
      wv.z = x[(size_t)(c4+2)*NPTS + idx]; wv.w = x[(size_t)(c4+3)*NPTS + idx];
    } else {
      wv.x = pos[idx] - sup0; wv.y = pos[NPTS + idx] - sup1;
      wv.z = pos[2*NPTS + idx] - sup2; wv.w = 0.f;
    }
    *(float4*)&sfeat[k][c4] = wv;
  }
  const int h = t & 63, kg = t >> 6;
  float w1r[68];
  #pragma unroll
  for (int c = 0; c < 67; ++c) w1r[c] = W1[h*67 + c];
  w1r[67] = 0.f;
  const float bias1 = b1[h];
  __syncthreads();
  #pragma unroll
  for (int j = 0; j < 4; ++j) {
    const int k = kg*4 + j;
    float a = bias1;
    const float4* rr = (const float4*)sfeat[k];
    #pragma unroll
    for (int qq = 0; qq < 17; ++qq) {
      const float4 v = rr[qq];
      a += w1r[qq*4+0]*v.x + w1r[qq*4+1]*v.y + w1r[qq*4+2]*v.z + w1r[qq*4+3]*v.w;
    }
    shid[k][h] = fmaxf(a, 0.f);
  }
  const int ow = t & 63;
  float w2a[64], w2b[64];
  #pragma unroll
  for (int hh = 0; hh < 64; ++hh) { w2a[hh] = W2[ow*64 + hh]; w2b[hh] = W2[(ow+64)*64 + hh]; }
  __syncthreads();
  float mxa = -3.0e38f, mxb = -3.0e38f;
  #pragma unroll
  for (int j = 0; j < 4; ++j) {
    const int k = kg*4 + j;
    const float4* hr = (const float4*)shid[k];
    float pa = 0.f, pb = 0.f;
    #pragma unroll
    for (int qq = 0; qq < 16; ++qq) {
      const float4 v = hr[qq];
      pa += w2a[qq*4+0]*v.x + w2a[qq*4+1]*v.y + w2a[qq*4+2]*v.z + w2a[qq*4+3]*v.w;
      pb += w2b[qq*4+0]*v.x + w2b[qq*4+1]*v.y + w2b[qq*4+2]*v.z + w2b[qq*4+3]*v.w;
    }
    mxa = fmaxf(mxa, pa); mxb = fmaxf(mxb, pb);
  }
  smax[kg][ow] = mxa; smax[kg][64 + ow] = mxb;
  __syncthreads();
  if (t < 128) {
    out[(size_t)t * MPTS + m] =
        fmaxf(fmaxf(smax[0][t], smax[1][t]), fmaxf(smax[2][t], smax[3][t])) + b2[t];
  }
}

extern "C" void kernel_launch(void* const* d_in, const int* in_sizes, int n_in,
                              void* d_out, int out_size, void* d_ws, size_t ws_size,
                              hipStream_t stream) {
  const float* x   = (const float*)d_in[0];
  const float* pos = (const float*)d_in[1];
  const float* sup = (const float*)d_in[2];
  const float* W1  = (const float*)d_in[3];
  const float* b1  = (const float*)d_in[4];
  const float* W2  = (const float*)d_in[5];
  const float* b2  = (const float*)d_in[6];
  const int* indices = (const int*)d_in[7];
  float* out = (float*)d_out;

  const size_t U_BYTES   = (size_t)NPTS * 64 * 2;     // 8,388,608
  const size_t W2F_BYTES = 16 * 64 * 8 * 2;           // 16,384
  if (ws_size >= U_BYTES + W2F_BYTES) {
    unsigned short* U   = (unsigned short*)d_ws;
    unsigned short* W2F = (unsigned short*)((char*)d_ws + U_BYTES);
    pack_u<<<NPTS/64 + 4, 256, 0, stream>>>(x, pos, W1, b1, W2, U, W2F);
    pointnet_reg<<<MPTS/32, 256, 0, stream>>>(U, sup, W1, W2F, b2, indices, out);
  } else {
    pointnet_fallback<<<MPTS, 256, 0, stream>>>(x, pos, sup, W1, b1, W2, b2, indices, out);
  }
}